// Round 6
// baseline (134.949 us; speedup 1.0000x reference)
//
#include <hip/hip_runtime.h>
#include <math.h>

#define BATCH 2048
#define SEQ 512
#define DIM 128

typedef float fx4 __attribute__((ext_vector_type(4)));  // native vec: nontemporal-load OK

// DPP rotate-within-16 add: after ror 1,2,4,8 every lane holds its 16-group sum.
template<int CTRL>
__device__ __forceinline__ float dpp_add(float x) {
    int y = __builtin_amdgcn_update_dpp(0, __float_as_int(x), CTRL, 0xf, 0xf, true);
    return x + __int_as_float(y);
}

// ws layout: [0..127] qk (SCALE*log2e), [128..131] qp, [132] c0 — all exp2-prescaled
__global__ __launch_bounds__(256) void ap_prep(
    const float* __restrict__ query,
    const float* __restrict__ Wk, const float* __restrict__ bk,
    const float* __restrict__ Wp, const float* __restrict__ bp,
    float* __restrict__ ws)
{
    __shared__ float part[128];
    __shared__ float pq[128][4];
    __shared__ float pc[128];
    const float S2 = 0.08838834764831845f * 1.4426950408889634f;  // 128^-0.5 * log2(e)
    const int t = threadIdx.x;
    const int d = t & 127, hk = t >> 7;   // 2 threads per output d, k-split
    float acc = 0.f;
    const int k0 = hk * 64;
    #pragma unroll 16
    for (int k = 0; k < 64; ++k) acc += query[k0 + k] * Wk[(k0 + k) * 128 + d];
    if (hk) part[d] = acc;
    if (t < 128) {
        float q = query[t];
        float4 wp = ((const float4*)Wp)[t];
        pq[t][0] = q * wp.x; pq[t][1] = q * wp.y;
        pq[t][2] = q * wp.z; pq[t][3] = q * wp.w;
        pc[t] = q * (bk[t] + bp[t]);
    }
    __syncthreads();
    if (!hk) {
        ws[d] = (acc + part[d]) * S2;
    } else if (d < 4) {
        float s = 0.f;
        #pragma unroll
        for (int k = 0; k < 128; ++k) s += pq[k][d];
        ws[128 + d] = s * S2;
    } else if (d == 4) {
        float s = 0.f;
        #pragma unroll
        for (int k = 0; k < 128; ++k) s += pc[k];
        ws[132] = s * S2;
    }
}

__global__ __launch_bounds__(256, 8) void ap_main(
    const float* __restrict__ x, const float* __restrict__ pos,
    const int* __restrict__ mask,
    const float* __restrict__ Wv, const float* __restrict__ bv,
    const float* __restrict__ ws, float* __restrict__ out)
{
    __shared__ float spos[SEQ];
    __shared__ float sacc[16][132];        // +4 pad: bank-shift rows
    __shared__ float sm[16], sl[16];
    __shared__ alignas(16) float t[DIM];

    const int b   = blockIdx.x;
    const int tid = threadIdx.x;
    const int w   = tid >> 6;              // wave 0..3, owns rows [128w, 128w+128)
    const int g   = (tid >> 4) & 3;        // 16-lane group: row g of each 4-row step
    const int ln  = tid & 15;              // lane within group: owns floats [4ln,4ln+4)+[64+4ln,..)
    const int sid = tid >> 4;              // softmax state 0..15

    // fx4 index of this lane's A-piece of row (4i+g) is i*128 + rb; B at +16
    const fx4* xw = (const fx4*)(x + (size_t)b * SEQ * DIM) + w * 4096;
    const int rb = g * 32 + ln;

#define LD(i, VA, VB)                                                         \
    {                                                                         \
        VA = __builtin_nontemporal_load(xw + (((i) & 31) * 128 + rb));        \
        VB = __builtin_nontemporal_load(xw + (((i) & 31) * 128 + rb + 16));   \
    }

    // issue the first 4 steps' loads immediately (hide the spos phase)
    fx4 vA0, vB0, vA1, vB1, vA2, vB2, vA3, vB3;
    LD(0, vA0, vB0); LD(1, vA1, vB1); LD(2, vA2, vB2); LD(3, vA3, vB3);

    const float4 qkA = ((const float4*)ws)[ln];
    const float4 qkB = ((const float4*)ws)[ln + 16];
    const float qp0 = ws[128], qp1 = ws[129], qp2 = ws[130], qp3 = ws[131];
    const float c0  = ws[132];

    // positional score (+c0), exp2-prescaled, masked
    #pragma unroll
    for (int s = tid; s < SEQ; s += 256) {
        float4 p4 = ((const float4*)pos)[(size_t)b * SEQ + s];
        float sc = fmaf(qp0, p4.x, fmaf(qp1, p4.y, fmaf(qp2, p4.z, fmaf(qp3, p4.w, c0))));
        if (mask[(size_t)b * SEQ + s] == 0) sc = -1e30f;
        spos[s] = sc;
    }
    __syncthreads();

    const int sp0 = w * 128 + g;           // spos index of this group's row at step 0

    float m = -INFINITY, den = 0.f;
    fx4 aA = {0.f, 0.f, 0.f, 0.f}, aB = {0.f, 0.f, 0.f, 0.f};

#define PROC(VA, VB, J)                                                       \
    {                                                                         \
        float r = (VA).x * qkA.x;                                             \
        r = fmaf((VA).y, qkA.y, r);                                           \
        r = fmaf((VA).z, qkA.z, r);                                           \
        r = fmaf((VA).w, qkA.w, r);                                           \
        r = fmaf((VB).x, qkB.x, r);                                           \
        r = fmaf((VB).y, qkB.y, r);                                           \
        r = fmaf((VB).z, qkB.z, r);                                           \
        r = fmaf((VB).w, qkB.w, r);                                           \
        r = dpp_add<0x121>(r);                                                \
        r = dpp_add<0x122>(r);                                                \
        r = dpp_add<0x124>(r);                                                \
        r = dpp_add<0x128>(r);                                                \
        float sc = r + spos[sp0 + 4 * (J)];                                   \
        float d  = sc - m;                                                    \
        if (__builtin_expect(d > 8.0f, 0)) {                                  \
            float f = __builtin_amdgcn_exp2f(-d);                             \
            den = fmaf(den, f, 1.0f);                                         \
            aA.x = fmaf(aA.x, f, (VA).x); aA.y = fmaf(aA.y, f, (VA).y);       \
            aA.z = fmaf(aA.z, f, (VA).z); aA.w = fmaf(aA.w, f, (VA).w);       \
            aB.x = fmaf(aB.x, f, (VB).x); aB.y = fmaf(aB.y, f, (VB).y);       \
            aB.z = fmaf(aB.z, f, (VB).z); aB.w = fmaf(aB.w, f, (VB).w);       \
            m = sc;                                                           \
        } else {                                                              \
            float p = __builtin_amdgcn_exp2f(d);                              \
            den += p;                                                         \
            aA.x = fmaf(p, (VA).x, aA.x); aA.y = fmaf(p, (VA).y, aA.y);       \
            aA.z = fmaf(p, (VA).z, aA.z); aA.w = fmaf(p, (VA).w, aA.w);       \
            aB.x = fmaf(p, (VB).x, aB.x); aB.y = fmaf(p, (VB).y, aB.y);       \
            aB.z = fmaf(p, (VB).z, aB.z); aB.w = fmaf(p, (VB).w, aB.w);       \
        }                                                                     \
    }

    // ---- 4-deep rotating pipeline over 8 chunks (32 steps × 4 rows) ----
    #pragma unroll
    for (int ch = 0; ch < 8; ++ch) {
        const int base = 4 * ch;
        PROC(vA0, vB0, base + 0); LD(base + 4, vA0, vB0);
        PROC(vA1, vB1, base + 1); LD(base + 5, vA1, vB1);
        PROC(vA2, vB2, base + 2); LD(base + 6, vA2, vB2);
        PROC(vA3, vB3, base + 3); LD(base + 7, vA3, vB3);
    }
#undef PROC
#undef LD

    // ---- merge the 16 states ----
    if (ln == 0) { sm[sid] = m; sl[sid] = den; }
    __syncthreads();
    float gm = -INFINITY;
    #pragma unroll
    for (int k = 0; k < 16; ++k) gm = fmaxf(gm, sm[k]);
    float f = __builtin_amdgcn_exp2f(m - gm);
    sacc[sid][4 * ln + 0]      = aA.x * f;
    sacc[sid][4 * ln + 1]      = aA.y * f;
    sacc[sid][4 * ln + 2]      = aA.z * f;
    sacc[sid][4 * ln + 3]      = aA.w * f;
    sacc[sid][64 + 4 * ln + 0] = aB.x * f;
    sacc[sid][64 + 4 * ln + 1] = aB.y * f;
    sacc[sid][64 + 4 * ln + 2] = aB.z * f;
    sacc[sid][64 + 4 * ln + 3] = aB.w * f;
    float gl = 0.f;
    #pragma unroll
    for (int k = 0; k < 16; ++k) gl += sl[k] * __builtin_amdgcn_exp2f(sm[k] - gm);
    __syncthreads();

    if (tid < DIM) {
        float s0 = 0.f;
        #pragma unroll
        for (int k = 0; k < 16; ++k) s0 += sacc[k][tid];
        t[tid] = s0;
    }
    __syncthreads();

    // ---- epilogue: pooled[b,k] = bv[k] + (Wv[k,:] . t) / gl ----
    if (tid < DIM) {
        const float4* wv4 = (const float4*)(Wv + tid * DIM);
        const float4* t4  = (const float4*)t;
        float sum = 0.f;
        #pragma unroll
        for (int j = 0; j < 32; ++j) {
            float4 wv = wv4[j];
            float4 tv = t4[j];
            sum += wv.x * tv.x + wv.y * tv.y + wv.z * tv.z + wv.w * tv.w;
        }
        out[(size_t)b * DIM + tid] = bv[tid] + sum / gl;
    }
}

extern "C" void kernel_launch(void* const* d_in, const int* in_sizes, int n_in,
                              void* d_out, int out_size, void* d_ws, size_t ws_size,
                              hipStream_t stream) {
    const float* x     = (const float*)d_in[0];
    const float* pos   = (const float*)d_in[1];
    const int*   mask  = (const int*)d_in[2];     // bool -> int32 per harness convention
    const float* query = (const float*)d_in[3];
    const float* Wk    = (const float*)d_in[4];
    const float* bk    = (const float*)d_in[5];
    const float* Wv    = (const float*)d_in[6];
    const float* bv    = (const float*)d_in[7];
    const float* Wp    = (const float*)d_in[8];
    const float* bp    = (const float*)d_in[9];
    float* out = (float*)d_out;
    float* ws  = (float*)d_ws;

    ap_prep<<<1, 256, 0, stream>>>(query, Wk, bk, Wp, bp, ws);
    ap_main<<<BATCH, 256, 0, stream>>>(x, pos, mask, Wv, bv, ws, out);
}